// Round 3
// baseline (8541.636 us; speedup 1.0000x reference)
//
#include <hip/hip_runtime.h>

// ---------------------------------------------------------------------------
// Lorentz transformer decoder forward. B=4 S=1024 V=32000 D=1040 H=16 HD=65 L=4
// GEMMs: split-bf16 MFMA (A ~ Ah+Al, W ~ Wh+Wl; 3 bf16 MFMAs emulate fp32).
// Attention / norms / rope: fp32 vector.
// Scratch: d_out doubles as scratch (dead before final vocab GEMM). d_ws holds
// X + (if ws_size >= ~170 MB) the vocab GEMM's split operands; else the vocab
// GEMM falls back to the fp32 vector path.
// ---------------------------------------------------------------------------

#define EPSF 1e-6f
#define RS_F 64.498061986388395f          // 2*sqrt(1040)
#define ISQ65 0.12403473458920847f        // 1/sqrt(65)

typedef __attribute__((ext_vector_type(8))) short bf16x8;
typedef __attribute__((ext_vector_type(4))) float f32x4;

__device__ __forceinline__ unsigned short f2bf(float x) {
  unsigned u = __float_as_uint(x);
  unsigned r = (u + 0x7FFFu + ((u >> 16) & 1u)) >> 16;   // round-nearest-even
  return (unsigned short)r;
}
__device__ __forceinline__ float bf2f(unsigned short h) {
  return __uint_as_float(((unsigned)h) << 16);
}

// ---------------- block reduction (256 threads / 4 waves) ------------------
__device__ __forceinline__ float block_sum_256(float v, float* s4) {
  #pragma unroll
  for (int m = 32; m >= 1; m >>= 1) v += __shfl_xor(v, m, 64);
  const int tid = threadIdx.x;
  if ((tid & 63) == 0) s4[tid >> 6] = v;
  __syncthreads();
  float r = s4[0] + s4[1] + s4[2] + s4[3];
  __syncthreads();
  return r;
}

// ---------------- rope tables ----------------------------------------------
__global__ void rope_table_k(float* __restrict__ cosT, float* __restrict__ sinT) {
  int idx = blockIdx.x * 256 + threadIdx.x;
  if (idx >= 1024 * 32) return;
  int p = idx >> 5, i = idx & 31;
  float inv = 1.0f / powf(10000.0f, (float)(2 * i) / 64.0f);
  float fr = (float)p * inv;
  cosT[idx] = cosf(fr);
  sinT[idx] = sinf(fr);
}

// ---------------- embedding + add_time -------------------------------------
__global__ void embed_k(const int* __restrict__ tok, const float* __restrict__ tab,
                        float* __restrict__ x) {
  __shared__ float s4[4];
  const int row = blockIdx.x, tid = threadIdx.x;
  const float* e = tab + (size_t)tok[row] * 1039;
  float v[5];
  float ss = 0.f;
  #pragma unroll
  for (int i = 0; i < 5; ++i) {
    int c = tid + i * 256;
    float val = (c < 1039) ? e[c] : 0.f;
    v[i] = val;
    ss += val * val;
  }
  float tot = block_sum_256(ss, s4);
  float* xr = x + (size_t)row * 1040;
  if (tid == 0) xr[0] = sqrtf(1.f + tot);
  #pragma unroll
  for (int i = 0; i < 5; ++i) {
    int c = tid + i * 256;
    if (c < 1039) xr[1 + c] = v[i];
  }
}

// ---------------- l_rmsnorm: in(.,1040) -> out(.,1040) ---------------------
__global__ void rmsnorm_k(const float* __restrict__ in, const float* __restrict__ w,
                          float* __restrict__ out) {
  __shared__ float s4[4];
  const int row = blockIdx.x, tid = threadIdx.x;
  const float* ir = in + (size_t)row * 1040;
  float xs[5];
  float ss = 0.f;
  #pragma unroll
  for (int i = 0; i < 5; ++i) {
    int c = tid + i * 256;
    float val = (c < 1039) ? ir[1 + c] : 0.f;
    xs[i] = val;
    ss += val * val;
  }
  float tot = block_sum_256(ss, s4);
  float r = 1.0f / sqrtf(tot / 1039.f + EPSF);
  float y[5];
  float ss2 = 0.f;
  #pragma unroll
  for (int i = 0; i < 5; ++i) {
    int c = tid + i * 256;
    float val = 0.f;
    if (c < 1039) {
      val = xs[i] * r * w[c];
      ss2 += val * val;
    }
    y[i] = val;
  }
  float tot2 = block_sum_256(ss2, s4);
  float* orow = out + (size_t)row * 1040;
  if (tid == 0) orow[0] = sqrtf(1.f + tot2);
  #pragma unroll
  for (int i = 0; i < 5; ++i) {
    int c = tid + i * 256;
    if (c < 1039) orow[1 + c] = y[i];
  }
}

// ---------------- lresnet: x = l_normalize(x + add_time(lin)/RS) -----------
__global__ void lresnet_k(float* __restrict__ x, const float* __restrict__ lin, int ldl) {
  __shared__ float s4[4];
  const int row = blockIdx.x, tid = threadIdx.x;
  const float* lr = lin + (size_t)row * ldl;
  float* xr = x + (size_t)row * 1040;
  float lv[5];
  float ss = 0.f;
  #pragma unroll
  for (int i = 0; i < 5; ++i) {
    int c = tid + i * 256;
    float val = (c < 1039) ? lr[c] : 0.f;
    lv[i] = val;
    ss += val * val;
  }
  float tot = block_sum_256(ss, s4);
  float t = sqrtf(1.f + tot);
  float z0 = xr[0] + t / RS_F;
  float zv[5];
  float ss2 = 0.f;
  #pragma unroll
  for (int i = 0; i < 5; ++i) {
    int c = tid + i * 256;
    float z = 0.f;
    if (c < 1039) {
      z = xr[1 + c] + lv[i] / RS_F;
      ss2 += z * z;
    }
    zv[i] = z;
  }
  float sp = block_sum_256(ss2, s4);
  float f = 1.0f / sqrtf(fmaxf(z0 * z0 - sp, EPSF));
  if (tid == 0) xr[0] = z0 * f;
  #pragma unroll
  for (int i = 0; i < 5; ++i) {
    int c = tid + i * 256;
    if (c < 1039) xr[1 + c] = zv[i] * f;
  }
}

// ---------------- add_time: in(.,N) -> out(.,N+1) --------------------------
__global__ void addtime_k(const float* __restrict__ in, int ldi, int N,
                          float* __restrict__ out, int ldo) {
  __shared__ float s4[4];
  const int row = blockIdx.x, tid = threadIdx.x;
  const float* ir = in + (size_t)row * ldi;
  float* orow = out + (size_t)row * ldo;
  float ss = 0.f;
  for (int c = tid; c < N; c += 256) {
    float v = ir[c];
    ss += v * v;
  }
  float tot = block_sum_256(ss, s4);
  if (tid == 0) orow[0] = sqrtf(1.f + tot);
  for (int c = tid; c < N; c += 256) orow[1 + c] = ir[c];
}

// ---------------- activation split: fp32 [M][ldin] -> bf16 hi/lo [M][Kp] ---
__global__ void asplit_k(const float* __restrict__ in, int ldin, int K, int Kp,
                         unsigned short* __restrict__ H, unsigned short* __restrict__ L) {
  const int row = blockIdx.x, tid = threadIdx.x;
  const float* ir = in + (size_t)row * ldin;
  unsigned short* hr = H + (size_t)row * Kp;
  unsigned short* lr = L + (size_t)row * Kp;
  for (int c = tid; c < Kp; c += 256) {
    float v = (c < K) ? ir[c] : 0.f;
    unsigned short h = f2bf(v);
    unsigned short l = f2bf(v - bf2f(h));
    hr[c] = h;
    lr[c] = l;
  }
}

// ---------------- weight transpose-split: W[K][N] -> Wt hi/lo [Np][Kp] -----
// grid: (ceil(Kp/64), Np/64), block 256.
__global__ void tsplit_k(const float* __restrict__ W, int ldw, int K, int N, int Kp,
                         unsigned short* __restrict__ H, unsigned short* __restrict__ L) {
  __shared__ float tile[64][65];
  const int tid = threadIdx.x;
  const int k0 = blockIdx.x * 64, n0 = blockIdx.y * 64;
  const int c = tid & 63, r0 = tid >> 6;
  #pragma unroll
  for (int i = 0; i < 16; ++i) {
    const int k = k0 + r0 + 4 * i;
    const int n = n0 + c;
    tile[r0 + 4 * i][c] = (k < K && n < N) ? W[(size_t)k * ldw + n] : 0.f;
  }
  __syncthreads();
  #pragma unroll
  for (int i = 0; i < 16; ++i) {
    const int n = n0 + r0 + 4 * i;          // output row (N dim)
    const int k = k0 + c;                   // output col (K dim)
    if (k < Kp) {
      float v = tile[c][r0 + 4 * i];
      unsigned short h = f2bf(v);
      unsigned short l = f2bf(v - bf2f(h));
      H[(size_t)n * Kp + k] = h;
      L[(size_t)n * Kp + k] = l;
    }
  }
}

// ---------------- rope + add_time + (B,S,*) -> (B,H,S,65) ------------------
__global__ void rope_addtime_k(const float* __restrict__ lin, int ldl,
                               const float* __restrict__ cosT,
                               const float* __restrict__ sinT,
                               float* __restrict__ outp, int do_rope) {
  const int row = blockIdx.x;            // b*1024 + s
  const int t = threadIdx.x;             // 0..511
  const int h = t >> 5, i = t & 31;
  const int s = row & 1023, b = row >> 10;
  const size_t ibase = (size_t)row * ldl + h * 64 + 2 * i;
  float x1 = lin[ibase];
  float x2 = lin[ibase + 1];
  float r1 = x1, r2 = x2;
  if (do_rope) {
    float c = cosT[s * 32 + i], sn = sinT[s * 32 + i];
    r1 = x1 * c - x2 * sn;
    r2 = x1 * sn + x2 * c;
  }
  float ss = r1 * r1 + r2 * r2;
  #pragma unroll
  for (int m = 16; m >= 1; m >>= 1) ss += __shfl_xor(ss, m, 32);
  const size_t orow = (((size_t)b * 16 + h) * 1024 + s) * 65;
  outp[orow + 1 + 2 * i] = r1;
  outp[orow + 2 + 2 * i] = r2;
  if (i == 0) outp[orow] = sqrtf(1.f + ss);
}

// ---------------- flash attention (Minkowski scores) + l_normalize ---------
__global__ __launch_bounds__(256, 3) void attn_k(const float* __restrict__ Q,
                                                 const float* __restrict__ K,
                                                 const float* __restrict__ V,
                                                 float* __restrict__ out) {
  __shared__ float Qs[64][67];
  __shared__ float Ks[64][67];
  __shared__ float Vs[64][67];
  const int tid = threadIdx.x;
  const int qt = blockIdx.x, h = blockIdx.y, b = blockIdx.z;
  const size_t bh = ((size_t)b * 16 + h) * 1024;
  const float* Qg = Q + (bh + (size_t)qt * 64) * 65;

  for (int idx = tid; idx < 64 * 65; idx += 256) Qs[idx / 65][idx % 65] = Qg[idx];
  __syncthreads();

  const int r = tid >> 2, qq = tid & 3;
  const int qg = qt * 64 + r;
  const int start = (qq == 0) ? 0 : (1 + qq * 16);
  const int len = (qq == 0) ? 17 : 16;

  float qreg[65];
  #pragma unroll
  for (int d = 0; d < 65; ++d) qreg[d] = Qs[r][d];
  qreg[0] = -qreg[0];

  float O[17];
  #pragma unroll
  for (int j = 0; j < 17; ++j) O[j] = 0.f;
  float m_run = -1e30f, l_run = 0.f;

  for (int kt = 0; kt <= qt; ++kt) {
    __syncthreads();
    const float* Kg = K + (bh + (size_t)kt * 64) * 65;
    const float* Vg = V + (bh + (size_t)kt * 64) * 65;
    for (int idx = tid; idx < 64 * 65; idx += 256) {
      Ks[idx / 65][idx % 65] = Kg[idx];
      Vs[idx / 65][idx % 65] = Vg[idx];
    }
    __syncthreads();

    float sc[16];
    float mx = -1e30f;
    #pragma unroll
    for (int j = 0; j < 16; ++j) {
      const int c = qq * 16 + j;
      float acc = 0.f;
      #pragma unroll
      for (int d = 0; d < 65; ++d) acc += qreg[d] * Ks[c][d];
      acc *= ISQ65;
      if (kt * 64 + c > qg) acc = -1e30f;
      sc[j] = acc;
      mx = fmaxf(mx, acc);
    }
    mx = fmaxf(mx, __shfl_xor(mx, 1, 4));
    mx = fmaxf(mx, __shfl_xor(mx, 2, 4));
    const float m_new = fmaxf(m_run, mx);
    const float fac = expf(m_run - m_new);
    float pv[16];
    float ps = 0.f;
    #pragma unroll
    for (int j = 0; j < 16; ++j) {
      pv[j] = expf(sc[j] - m_new);
      ps += pv[j];
    }
    ps += __shfl_xor(ps, 1, 4);
    ps += __shfl_xor(ps, 2, 4);
    l_run = l_run * fac + ps;
    m_run = m_new;
    #pragma unroll
    for (int j = 0; j < 17; ++j) O[j] *= fac;
    #pragma unroll
    for (int j = 0; j < 16; ++j) Qs[r][qq * 16 + j] = pv[j];
    __syncthreads();
    for (int c = 0; c < 64; ++c) {
      const float p = Qs[r][c];
      #pragma unroll
      for (int j = 0; j < 17; ++j)
        if (j < len) O[j] += p * Vs[c][start + j];
    }
  }

  const float linv = 1.f / l_run;
  #pragma unroll
  for (int j = 0; j < 17; ++j) O[j] *= linv;

  float ssq = 0.f;
  #pragma unroll
  for (int j = 0; j < 17; ++j)
    if (j < len && !(qq == 0 && j == 0)) ssq += O[j] * O[j];
  ssq += __shfl_xor(ssq, 1, 4);
  ssq += __shfl_xor(ssq, 2, 4);
  const float z0 = __shfl(O[0], 0, 4);
  const float f = 1.0f / sqrtf(fmaxf(z0 * z0 - ssq, EPSF));
  float* Or = out + ((size_t)b * 1024 + qg) * 1040 + h * 65;
  #pragma unroll
  for (int j = 0; j < 17; ++j)
    if (j < len) Or[start + j] = O[j] * f;
}

// ---------------- split-bf16 MFMA GEMM -------------------------------------
// C[4096][ldc] = A[4096][Kp]·Wt^T + bias (Wt stored [Np][Kp]), optional gelu.
// block 256 = 4 waves; tile 128x128; wave sub-tile 64x64 (4x4 frags 16x16).
// A ~ Ah+Al, W ~ Wh+Wl (bf16): acc += Ah·Wh + Al·Wh + Ah·Wl.
#define LDP 40   // LDS row pitch (ushort): 80 B, 16B-aligned, bank-spread

__device__ __forceinline__ float gelu_f(float v) {
  float u = 0.7978845608028654f * (v + 0.044715f * v * v * v);
  return 0.5f * v * (1.0f + tanhf(u));
}

__global__ __launch_bounds__(256, 2) void gemm_mfma_k(
    const unsigned short* __restrict__ AH, const unsigned short* __restrict__ AL,
    const unsigned short* __restrict__ WH, const unsigned short* __restrict__ WL,
    int Kp, const float* __restrict__ b0, const float* __restrict__ b1,
    const float* __restrict__ b2, int qkv_bias,
    float* __restrict__ C, int ldc, int N, int act) {
  __shared__ unsigned short sAH[128 * LDP], sAL[128 * LDP];
  __shared__ unsigned short sBH[128 * LDP], sBL[128 * LDP];
  const int tid = threadIdx.x;
  const int bn = blockIdx.x * 128, bm = blockIdx.y * 128;
  const int wave = tid >> 6, lane = tid & 63;
  const int wr = (wave >> 1) * 64, wc = (wave & 1) * 64;
  const int l15 = lane & 15, l4 = lane >> 4;

  const int srow = tid >> 1, scol = (tid & 1) * 16;   // staging: 2 thr/row, 16 ushort each
  const size_t aoff = (size_t)(bm + srow) * Kp + scol;
  const size_t boff = (size_t)(bn + srow) * Kp + scol;
  const int sidx = srow * LDP + scol;

  f32x4 acc[4][4];
  #pragma unroll
  for (int i = 0; i < 4; ++i)
    #pragma unroll
    for (int j = 0; j < 4; ++j) acc[i][j] = (f32x4)0.f;

  union U { uint2 u2[2]; bf16x8 v; };

  for (int k0 = 0; k0 < Kp; k0 += 32) {
    uint4 gah0 = *(const uint4*)(AH + aoff + k0);
    uint4 gah1 = *(const uint4*)(AH + aoff + k0 + 8);
    uint4 gal0 = *(const uint4*)(AL + aoff + k0);
    uint4 gal1 = *(const uint4*)(AL + aoff + k0 + 8);
    uint4 gbh0 = *(const uint4*)(WH + boff + k0);
    uint4 gbh1 = *(const uint4*)(WH + boff + k0 + 8);
    uint4 gbl0 = *(const uint4*)(WL + boff + k0);
    uint4 gbl1 = *(const uint4*)(WL + boff + k0 + 8);
    __syncthreads();
    *(uint4*)&sAH[sidx] = gah0; *(uint4*)&sAH[sidx + 8] = gah1;
    *(uint4*)&sAL[sidx] = gal0; *(uint4*)&sAL[sidx + 8] = gal1;
    *(uint4*)&sBH[sidx] = gbh0; *(uint4*)&sBH[sidx + 8] = gbh1;
    *(uint4*)&sBL[sidx] = gbl0; *(uint4*)&sBL[sidx + 8] = gbl1;
    __syncthreads();

    bf16x8 ah[4], al[4], bh[4], bl[4];
    #pragma unroll
    for (int i = 0; i < 4; ++i) {
      const int rbase = (wr + i * 16 + l15) * LDP + l4 * 4;
      U t;
      t.u2[0] = *(const uint2*)&sAH[rbase];
      t.u2[1] = *(const uint2*)&sAH[rbase + 16];
      ah[i] = t.v;
      t.u2[0] = *(const uint2*)&sAL[rbase];
      t.u2[1] = *(const uint2*)&sAL[rbase + 16];
      al[i] = t.v;
    }
    #pragma unroll
    for (int j = 0; j < 4; ++j) {
      const int rbase = (wc + j * 16 + l15) * LDP + l4 * 4;
      U t;
      t.u2[0] = *(const uint2*)&sBH[rbase];
      t.u2[1] = *(const uint2*)&sBH[rbase + 16];
      bh[j] = t.v;
      t.u2[0] = *(const uint2*)&sBL[rbase];
      t.u2[1] = *(const uint2*)&sBL[rbase + 16];
      bl[j] = t.v;
    }
    #pragma unroll
    for (int i = 0; i < 4; ++i)
      #pragma unroll
      for (int j = 0; j < 4; ++j) {
        acc[i][j] = __builtin_amdgcn_mfma_f32_16x16x32_bf16(ah[i], bh[j], acc[i][j], 0, 0, 0);
        acc[i][j] = __builtin_amdgcn_mfma_f32_16x16x32_bf16(al[i], bh[j], acc[i][j], 0, 0, 0);
        acc[i][j] = __builtin_amdgcn_mfma_f32_16x16x32_bf16(ah[i], bl[j], acc[i][j], 0, 0, 0);
      }
  }

  #pragma unroll
  for (int i = 0; i < 4; ++i) {
    #pragma unroll
    for (int j = 0; j < 4; ++j) {
      const int col = bn + wc + j * 16 + l15;
      if (col < N) {
        float bias;
        if (qkv_bias) {
          const float* bp = (col >= 2048) ? b2 : (col >= 1024) ? b1 : b0;
          bias = bp[col & 1023];
        } else {
          bias = b0[col];
        }
        #pragma unroll
        for (int r2 = 0; r2 < 4; ++r2) {
          const int row = bm + wr + i * 16 + l4 * 4 + r2;
          float v = acc[i][j][r2] + bias;
          if (act) v = gelu_f(v);
          C[(size_t)row * ldc + col] = v;
        }
      }
    }
  }
}

// ---------------- fp32 vector SGEMM (vocab fallback only) ------------------
#define BM 128
#define BN 128
#define BK 8
#define LP 132

__global__ __launch_bounds__(256, 2) void gemm_k(const float* __restrict__ A, int lda,
                                                 const float* __restrict__ W, int ldw,
                                                 const float* __restrict__ bias,
                                                 float* __restrict__ C, int ldc,
                                                 int N, int K) {
  __shared__ float As[BK][LP];
  __shared__ float Bs[BK][LP];
  const int tid = threadIdx.x;
  const int bm = blockIdx.y * BM;
  const int bn = blockIdx.x * BN;
  const int tx = tid & 15, ty = tid >> 4;
  const int arow = tid >> 1, acol = (tid & 1) * 4;
  const int brow = tid >> 5, bcol = (tid & 31) * 4;
  const float* Ap = A + (size_t)(bm + arow) * lda;

  float acc[8][8];
  #pragma unroll
  for (int i = 0; i < 8; ++i)
    #pragma unroll
    for (int j = 0; j < 8; ++j) acc[i][j] = 0.f;

  for (int k0 = 0; k0 < K; k0 += BK) {
    const int ka = k0 + acol;
    float4 av;
    if (ka + 3 < K) {
      av = *(const float4*)(Ap + ka);
    } else {
      av.x = (ka + 0 < K) ? Ap[ka + 0] : 0.f;
      av.y = (ka + 1 < K) ? Ap[ka + 1] : 0.f;
      av.z = (ka + 2 < K) ? Ap[ka + 2] : 0.f;
      av.w = (ka + 3 < K) ? Ap[ka + 3] : 0.f;
    }
    const int kb = k0 + brow;
    const int nb = bn + bcol;
    float4 bv;
    if (kb < K) {
      bv = *(const float4*)(W + (size_t)kb * ldw + nb);
    } else {
      bv.x = bv.y = bv.z = bv.w = 0.f;
    }
    __syncthreads();
    As[acol + 0][arow] = av.x;
    As[acol + 1][arow] = av.y;
    As[acol + 2][arow] = av.z;
    As[acol + 3][arow] = av.w;
    *(float4*)&Bs[brow][bcol] = bv;
    __syncthreads();
    #pragma unroll
    for (int k = 0; k < BK; ++k) {
      float a[8], bb[8];
      *(float4*)&a[0] = *(const float4*)&As[k][ty * 8];
      *(float4*)&a[4] = *(const float4*)&As[k][ty * 8 + 4];
      *(float4*)&bb[0] = *(const float4*)&Bs[k][tx * 8];
      *(float4*)&bb[4] = *(const float4*)&Bs[k][tx * 8 + 4];
      #pragma unroll
      for (int i = 0; i < 8; ++i)
        #pragma unroll
        for (int j = 0; j < 8; ++j) acc[i][j] += a[i] * bb[j];
    }
  }

  #pragma unroll
  for (int i = 0; i < 8; ++i) {
    const int row = bm + ty * 8 + i;
    float* Cr = C + (size_t)row * ldc;
    #pragma unroll
    for (int j0 = 0; j0 < 8; j0 += 4) {
      const int col = bn + tx * 8 + j0;
      float4 o;
      o.x = acc[i][j0 + 0] + bias[col + 0];
      o.y = acc[i][j0 + 1] + bias[col + 1];
      o.z = acc[i][j0 + 2] + bias[col + 2];
      o.w = acc[i][j0 + 3] + bias[col + 3];
      *(float4*)(Cr + col) = o;
    }
  }
}

// ---------------------------------------------------------------------------
extern "C" void kernel_launch(void* const* d_in, const int* in_sizes, int n_in,
                              void* d_out, int out_size, void* d_ws, size_t ws_size,
                              hipStream_t stream) {
  (void)in_sizes; (void)n_in; (void)out_size;
  const int*   tok   = (const int*)  d_in[0];
  const float* emb   = (const float*)d_in[1];
  const float* ln1   = (const float*)d_in[2];
  const float* wq    = (const float*)d_in[3];
  const float* bq    = (const float*)d_in[4];
  const float* wk    = (const float*)d_in[5];
  const float* bk    = (const float*)d_in[6];
  const float* wv    = (const float*)d_in[7];
  const float* bv    = (const float*)d_in[8];
  const float* wo    = (const float*)d_in[9];
  const float* bo    = (const float*)d_in[10];
  const float* ln2   = (const float*)d_in[11];
  const float* w1    = (const float*)d_in[12];
  const float* b1    = (const float*)d_in[13];
  const float* w2    = (const float*)d_in[14];
  const float* b2    = (const float*)d_in[15];
  const float* lnf   = (const float*)d_in[16];
  const float* wproj = (const float*)d_in[17];
  const float* bproj = (const float*)d_in[18];
  const float* wmap  = (const float*)d_in[19];
  const float* bmap  = (const float*)d_in[20];
  float* outp = (float*)d_out;

  // ---- d_out scratch (floats; all dead before final vocab GEMM) ----
  float* Ab = outp;                                    // 17,043,456
  float* Cb = outp + 17043456;                         // 17,055,744
  float* T1 = outp + 34099200;                         //  4,259,840
  unsigned short* AH  = (unsigned short*)(outp + 38359040);  // [4096][<=4192] bf16
  unsigned short* AL  = (unsigned short*)(outp + 46944256);
  unsigned short* WtH = (unsigned short*)(outp + 55529472);  // <=2.5M floats
  unsigned short* WtL = (unsigned short*)(outp + 58029472);
  float* cosT = outp + 60529472;
  float* sinT = cosT + 32768;

  // ---- d_ws: X always; vocab-GEMM split operands if ws is big enough ----
  float* X = (float*)d_ws;
  unsigned short* XHw = (unsigned short*)((float*)d_ws + 4259840);
  unsigned short* XLw = (unsigned short*)((float*)d_ws + 6422528);
  unsigned short* WmH = (unsigned short*)((float*)d_ws + 8585216);
  unsigned short* WmL = (unsigned short*)((float*)d_ws + 25481216);
  const bool big_ws = ws_size >= 169508864ull;

  rope_table_k<<<128, 256, 0, stream>>>(cosT, sinT);
  embed_k<<<4096, 256, 0, stream>>>(tok, emb, X);

  for (int l = 0; l < 4; ++l) {
    const float* wq_l = wq + (size_t)l * 1040 * 1024;
    const float* wk_l = wk + (size_t)l * 1040 * 1024;
    const float* wv_l = wv + (size_t)l * 1040 * 1024;
    const float* wo_l = wo + (size_t)l * 1040 * 1039;
    const float* w1_l = w1 + (size_t)l * 1040 * 4160;
    const float* w2_l = w2 + (size_t)l * 4161 * 1039;

    // ---- attention ----
    rmsnorm_k<<<4096, 256, 0, stream>>>(X, ln1 + (size_t)l * 1039, T1);
    asplit_k<<<4096, 256, 0, stream>>>(T1, 1040, 1040, 1056, AH, AL);
    tsplit_k<<<dim3(17, 16), 256, 0, stream>>>(wq_l, 1024, 1040, 1024, 1056,
                                               WtH, WtL);
    tsplit_k<<<dim3(17, 16), 256, 0, stream>>>(wk_l, 1024, 1040, 1024, 1056,
                                               WtH + (size_t)1024 * 1056, WtL + (size_t)1024 * 1056);
    tsplit_k<<<dim3(17, 16), 256, 0, stream>>>(wv_l, 1024, 1040, 1024, 1056,
                                               WtH + (size_t)2048 * 1056, WtL + (size_t)2048 * 1056);
    gemm_mfma_k<<<dim3(24, 32), 256, 0, stream>>>(AH, AL, WtH, WtL, 1056,
        bq + (size_t)l * 1024, bk + (size_t)l * 1024, bv + (size_t)l * 1024, 1,
        Ab, 3072, 3072, 0);

    rope_addtime_k<<<4096, 512, 0, stream>>>(Ab,        3072, cosT, sinT, Cb,           1);
    rope_addtime_k<<<4096, 512, 0, stream>>>(Ab + 1024, 3072, cosT, sinT, Cb + 4259840, 1);
    rope_addtime_k<<<4096, 512, 0, stream>>>(Ab + 2048, 3072, cosT, sinT, Cb + 8519680, 0);

    attn_k<<<dim3(16, 16, 4), 256, 0, stream>>>(Cb, Cb + 4259840, Cb + 8519680, T1);

    asplit_k<<<4096, 256, 0, stream>>>(T1, 1040, 1040, 1056, AH, AL);
    tsplit_k<<<dim3(17, 18), 256, 0, stream>>>(wo_l, 1039, 1040, 1039, 1056, WtH, WtL);
    gemm_mfma_k<<<dim3(9, 32), 256, 0, stream>>>(AH, AL, WtH, WtL, 1056,
        bo + (size_t)l * 1039, bo + (size_t)l * 1039, bo + (size_t)l * 1039, 0,
        Ab, 1040, 1039, 0);
    lresnet_k<<<4096, 256, 0, stream>>>(X, Ab, 1040);

    // ---- MLP ----
    rmsnorm_k<<<4096, 256, 0, stream>>>(X, ln2 + (size_t)l * 1039, T1);
    asplit_k<<<4096, 256, 0, stream>>>(T1, 1040, 1040, 1056, AH, AL);
    tsplit_k<<<dim3(17, 66), 256, 0, stream>>>(w1_l, 4160, 1040, 4160, 1056, WtH, WtL);
    gemm_mfma_k<<<dim3(33, 32), 256, 0, stream>>>(AH, AL, WtH, WtL, 1056,
        b1 + (size_t)l * 4160, b1 + (size_t)l * 4160, b1 + (size_t)l * 4160, 0,
        Ab, 4160, 4160, 1);
    addtime_k<<<4096, 256, 0, stream>>>(Ab, 4160, 4160, Cb, 4164);
    asplit_k<<<4096, 256, 0, stream>>>(Cb, 4164, 4161, 4192, AH, AL);
    tsplit_k<<<dim3(66, 18), 256, 0, stream>>>(w2_l, 1039, 4161, 1039, 4192, WtH, WtL);
    gemm_mfma_k<<<dim3(9, 32), 256, 0, stream>>>(AH, AL, WtH, WtL, 4192,
        b2 + (size_t)l * 1039, b2 + (size_t)l * 1039, b2 + (size_t)l * 1039, 0,
        Ab, 1040, 1039, 0);
    lresnet_k<<<4096, 256, 0, stream>>>(X, Ab, 1040);
  }

  // ---- head: proj -> add_time -> rmsnorm -> vocab GEMM ----
  asplit_k<<<4096, 256, 0, stream>>>(X, 1040, 1040, 1056, AH, AL);
  tsplit_k<<<dim3(17, 18), 256, 0, stream>>>(wproj, 1039, 1040, 1039, 1056, WtH, WtL);
  gemm_mfma_k<<<dim3(9, 32), 256, 0, stream>>>(AH, AL, WtH, WtL, 1056,
      bproj, bproj, bproj, 0, Ab, 1040, 1039, 0);
  addtime_k<<<4096, 256, 0, stream>>>(Ab, 1040, 1039, T1, 1040);
  rmsnorm_k<<<4096, 256, 0, stream>>>(T1, lnf, X);

  if (big_ws) {
    asplit_k<<<4096, 256, 0, stream>>>(X, 1040, 1040, 1056, XHw, XLw);
    tsplit_k<<<dim3(17, 500), 256, 0, stream>>>(wmap, 32000, 1040, 32000, 1056, WmH, WmL);
    gemm_mfma_k<<<dim3(250, 32), 256, 0, stream>>>(XHw, XLw, WmH, WmL, 1056,
        bmap, bmap, bmap, 0, outp, 32000, 32000, 0);
  } else {
    gemm_k<<<dim3(250, 32), 256, 0, stream>>>(X, 1040, wmap, 32000, bmap,
                                              outp, 32000, 32000, 1040);
  }
}